// Round 10
// baseline (70230.756 us; speedup 1.0000x reference)
//
#include <hip/hip_runtime.h>
#include <hip/hip_fp16.h>
#include <math.h>

#define NN 256
#define HH 64

typedef unsigned int uint32;

__device__ __forceinline__ float sigm(float x) { return 1.0f / (1.0f + expf(-x)); }

// packed f16 FMA: 2 MACs in one v_pk_fma_f16
__device__ __forceinline__ __half2 pkfma(uint32 a, uint32 b, __half2 c) {
    __half2 x = *reinterpret_cast<__half2*>(&a);
    __half2 y = *reinterpret_cast<__half2*>(&b);
    return __hfma2(x, y, c);
}

// wave-uniform lane read (SGPR broadcast)
__device__ __forceinline__ uint32 rdlane(uint32 v, int l) {
#if __has_builtin(__builtin_amdgcn_readlane)
    return (uint32)__builtin_amdgcn_readlane((int)v, l);
#else
    return (uint32)__shfl((int)v, l);
#endif
}

// ---------------- R construction (fp64 GEMM chain) — proven ----------------
__global__ void k_affine(const float* __restrict__ A, float* __restrict__ Pout,
                         const float* __restrict__ tev, int div)
{
    int i = blockIdx.x, j = threadIdx.x;
    double h = (double)tev[1] - (double)tev[0];
    double v = (i == j ? 1.0 : 0.0) + (h / (double)div) * (double)A[i * NN + j];
    Pout[i * NN + j] = (float)v;
}

__global__ void k_gemm(const float* __restrict__ A, const float* __restrict__ Pin,
                       float* __restrict__ Pout, const float* __restrict__ tev, int div)
{
    int i = blockIdx.x, j = threadIdx.x;
    double h = (double)tev[1] - (double)tev[0];
    const float* Ar = A + i * NN;
    double acc = 0.0;
    for (int k = 0; k < NN; ++k) acc += (double)Ar[k] * (double)Pin[k * NN + j];
    double v = (i == j ? 1.0 : 0.0) + (h / (double)div) * acc;
    Pout[i * NN + j] = (float)v;
}

// gq = [g0 | g1 | g2 | g3 | q | ce]  (ce = MU * rowsum(R - I), fp64) — proven
__global__ void k_prep_vec(const float* __restrict__ A, const float* __restrict__ B,
                           const float* __restrict__ cooling, const float* __restrict__ tev,
                           const float* __restrict__ R, float* __restrict__ gq)
{
    __shared__ float heat[NN];
    __shared__ float vin[NN];
    int t = threadIdx.x;
    double h = (double)tev[1] - (double)tev[0];
    heat[t] = (t < NN - 2) ? 500.0f * sigm(cooling[t]) : 0.0f;
    __syncthreads();
    float B0 = B[t * (NN - 1)];
    double bh = 0.0;
    for (int j = 0; j < NN - 2; ++j) bh += (double)B[t * (NN - 1) + 1 + j] * (double)heat[j];
    vin[t] = B0; __syncthreads();
    double v1 = 0.0; for (int k = 0; k < NN; ++k) v1 += (double)A[t * NN + k] * (double)vin[k];
    __syncthreads(); vin[t] = (float)v1; __syncthreads();
    double v2 = 0.0; for (int k = 0; k < NN; ++k) v2 += (double)A[t * NN + k] * (double)vin[k];
    __syncthreads(); vin[t] = (float)v2; __syncthreads();
    double v3 = 0.0; for (int k = 0; k < NN; ++k) v3 += (double)A[t * NN + k] * (double)vin[k];
    __syncthreads();
    vin[t] = (float)bh; __syncthreads();
    double u1 = 0.0; for (int k = 0; k < NN; ++k) u1 += (double)A[t * NN + k] * (double)vin[k];
    __syncthreads(); vin[t] = (float)u1; __syncthreads();
    double u2 = 0.0; for (int k = 0; k < NN; ++k) u2 += (double)A[t * NN + k] * (double)vin[k];
    __syncthreads(); vin[t] = (float)u2; __syncthreads();
    double u3 = 0.0; for (int k = 0; k < NN; ++k) u3 += (double)A[t * NN + k] * (double)vin[k];

    double srow = 0.0;
    for (int c = 0; c < NN; ++c) srow += (double)R[t * NN + c];
    srow -= 1.0;                               // rowsum(E)

    gq[t]        = (float)((h / 6.0) * (double)B0);
    gq[256 + t]  = (float)((h * h / 6.0) * v1);
    gq[512 + t]  = (float)((h * h * h / 12.0) * v2);
    gq[768 + t]  = (float)((h * h * h * h / 24.0) * v3);
    gq[1024 + t] = (float)(h * bh + (h * h / 2.0) * u1 + (h * h * h / 6.0) * u2
                           + (h * h * h * h / 24.0) * u3);
    gq[1280 + t] = (float)(23.359 * srow);
}

__device__ __forceinline__ float interp1(float x, const float* __restrict__ ts,
                                         const float* __restrict__ vs, int n)
{
    int lo = 0, hi = n;
    while (lo < hi) { int mid = (lo + hi) >> 1; if (ts[mid] <= x) lo = mid + 1; else hi = mid; }
    int i = lo; if (i < 1) i = 1; if (i > n - 1) i = n - 1;
    float xim = ts[i - 1], xi = ts[i];
    float fim = vs[i - 1], fi = vs[i];
    return fim + (x - xim) / (xi - xim) * (fi - fim);
}

// td[k][0..7] = {S0,S1,S2,S3, sinD,cosD,sinW,cosW} — proven
__global__ void k_time(const float* __restrict__ tev, const float* __restrict__ tts,
                       const float* __restrict__ tvals, float* __restrict__ td,
                       int T, int ntout)
{
    int k = blockIdx.x * blockDim.x + threadIdx.x;
    if (k >= T) return;
    float t0 = tev[0];
    float dtf = tev[1] - t0;
    float t = tev[k] - t0;
    const float cD = (float)(2.0 * M_PI / 86400.0);
    const float cW = (float)(2.0 * M_PI / 604800.0);
    float f0 = (float)sin((double)(t * cD));
    float f1 = (float)cos((double)(t * cD));
    float f2 = (float)sin((double)(t * cW));
    float f3 = (float)cos((double)(t * cW));
    float To1 = interp1(t + t0, tts, tvals, ntout);
    float To2 = interp1((t + 0.5f * dtf) + t0, tts, tvals, ntout);
    float To4 = interp1((t + dtf) + t0, tts, tvals, ntout);
    size_t o = (size_t)k * 8;
    td[o + 0] = To1 + 4.0f * To2 + To4;
    td[o + 1] = To1 + 2.0f * To2;
    td[o + 2] = To1 + To2;
    td[o + 3] = To1;
    td[o + 4] = f0; td[o + 5] = f1; td[o + 6] = f2; td[o + 7] = f3;
}

// Pack E = 64*(R - I) as f16 pairs for the 16-wave layout:
// thread t: w=t>>6, lane=t&63, qt=w>>2, g=w&3, r=g*64+lane;
// Epk[t*32+i] = pack{E[r][qt*64+2i], E[r][qt*64+2i+1]}
__global__ void k_packE(const float* __restrict__ R, uint32* __restrict__ Epk)
{
    int d = blockIdx.x * 256 + threadIdx.x;   // 0..32767
    int t = d >> 5, i = d & 31;
    int w = t >> 6, lane = t & 63;
    int qt = w >> 2, g = w & 3;
    int r = g * 64 + lane;
    int c = qt * 64 + 2 * i;
    float e0 = 64.0f * (R[r * NN + c]     - (r == c     ? 1.0f : 0.0f));
    float e1 = 64.0f * (R[r * NN + c + 1] - (r == c + 1 ? 1.0f : 0.0f));
    union { _Float16 h[2]; uint32 u; } p;
    p.h[0] = (_Float16)e0; p.h[1] = (_Float16)e1;
    Epk[d] = p.u;
}

// Pack w1 state-cols / 1.41 as f16 pairs, [slot s=0..7][row j=0..63][i=0..15]:
// w1pk[(s*64+j)*16+i] = pack{w1[j][32s+2i], w1[j][32s+2i+1]} / 1.41
__global__ void k_packW(const float* __restrict__ w1, uint32* __restrict__ w1pk)
{
    int m = blockIdx.x * 256 + threadIdx.x;   // 0..8191
    int s = m >> 10, j = (m >> 4) & 63, i = m & 15;
    int col = 32 * s + 2 * i;
    const float is = 1.0f / 1.41f;
    union { _Float16 h[2]; uint32 u; } p;
    p.h[0] = (_Float16)(w1[j * 260 + col] * is);
    p.h[1] = (_Float16)(w1[j * 260 + col + 1] * is);
    w1pk[m] = p.u;
}

// ---------------- Sequential integrator ----------------
// 1024 threads / 16 waves (4 waves/SIMD). Wave w: qt=w>>2 (x'-slice), g=w&3,
// row r=g*64+lane. Matvec: 1 LDS b32/lane + 32 readlane + 32 v_pk_fma_f16.
// Policy: waves 4-11, row=lane, 32-col chunk/wave, w1 in LDS.
// Stale policy: a_k = policy(x_{k-1}, t_k); a_0 exact via prologue. Wave 4
// computes a_{k+1} in Phase B concurrently with the x-update (latency hidden).
__global__ __launch_bounds__(1024) void k_main(
    const float* __restrict__ tdata, const uint32* Epk,
    const uint32* __restrict__ w1pk, const float* __restrict__ gq,
    const float* __restrict__ b1g, const float* __restrict__ w2g,
    const float* __restrict__ w1g, float* out, int T)
{
    __shared__ __align__(16) uint32 spk[128];   // x' f16 pairs
    __shared__ __align__(16) uint32 w1l[8192];  // packed w1 (32 KB)
    __shared__ float part[4][NN];
    __shared__ float hsp[8][HH];
    __shared__ float td[2][8];
    __shared__ float aS[2];

    const int t = threadIdx.x;
    const int w = t >> 6, lane = t & 63;
    const int qt = w >> 2, g = w & 3;
    const int r = g * 64 + lane;
    const bool pol = (w >= 4 && w < 12);
    const int cpol = w - 4;

    // E quarter-slice -> 32 dwords (f16 pairs, x64 scale)
    uint32 Ereg[32];
    {
        const uint4* Eg = reinterpret_cast<const uint4*>(Epk) + (size_t)t * 8;
        #pragma unroll
        for (int i = 0; i < 8; ++i) {
            uint4 v = Eg[i];
            Ereg[4 * i + 0] = v.x; Ereg[4 * i + 1] = v.y;
            Ereg[4 * i + 2] = v.z; Ereg[4 * i + 3] = v.w;
        }
    }
    // per-row combine constants (used by t<256)
    float g0r = gq[r], g1r = gq[256 + r], g2r = gq[512 + r], g3r = gq[768 + r];
    float qr = gq[1024 + r], cer = gq[1280 + r];
    // wave-4 action constants (per lane)
    float w1f0 = w1g[lane * 260 + 256], w1f1 = w1g[lane * 260 + 257];
    float w1f2 = w1g[lane * 260 + 258], w1f3 = w1g[lane * 260 + 259];
    float b1r = b1g[lane], w2r = w2g[lane];

    for (int i = t; i < 8192; i += 1024) w1l[i] = w1pk[i];

    __half* sph = reinterpret_cast<__half*>(spk);
    float xr = 26.0f;
    if (t < NN) sph[t] = __float2half_rn(26.0f - 23.359f);
    if (t < 8) td[0][t] = tdata[t];
    __syncthreads();

    const __half2 hzero = __floats2half2_rn(0.0f, 0.0f);

    // ---- prologue: exact a_0 = policy(x_0, t_0) ----
    if (pol) {
        uint32 xld2 = spk[cpol * 16 + (lane & 15)];
        const uint32* wl = w1l + (cpol * 64 + lane) * 16;
        __half2 a0 = hzero, a1 = hzero;
        #pragma unroll
        for (int i = 0; i < 8; ++i) {
            a0 = pkfma(wl[2 * i],     rdlane(xld2, 2 * i),     a0);
            a1 = pkfma(wl[2 * i + 1], rdlane(xld2, 2 * i + 1), a1);
        }
        hsp[cpol][lane] = __low2float(a0) + __high2float(a0)
                        + __low2float(a1) + __high2float(a1);
    }
    __syncthreads();
    if (w == 4) {
        float s = 0.0f;
        #pragma unroll
        for (int i = 0; i < 8; ++i) s += hsp[i][lane];
        float h = tanhf(s + b1r + w1f0 * td[0][4] + w1f1 * td[0][5]
                              + w1f2 * td[0][6] + w1f3 * td[0][7]);
        float v = w2r * h;
        v += __shfl_xor(v, 1);  v += __shfl_xor(v, 2);  v += __shfl_xor(v, 4);
        v += __shfl_xor(v, 8);  v += __shfl_xor(v, 16); v += __shfl_xor(v, 32);
        if (lane == 0) aS[0] = sigm(v);
    }
    __syncthreads();

    for (int k = 0; k < T; ++k) {
        const int cur = k & 1, nxt = cur ^ 1;
        float tdp = 0.0f;
        if (t >= 1016 && k + 1 < T) tdp = tdata[(size_t)(k + 1) * 8 + (t - 1016)];

        // ---- Phase A ----
        if (pol) {   // policy partials from x_k (feeds a_{k+1})
            uint32 xld2 = spk[cpol * 16 + (lane & 15)];
            const uint32* wl = w1l + (cpol * 64 + lane) * 16;
            __half2 a0 = hzero, a1 = hzero;
            #pragma unroll
            for (int i = 0; i < 8; ++i) {
                a0 = pkfma(wl[2 * i],     rdlane(xld2, 2 * i),     a0);
                a1 = pkfma(wl[2 * i + 1], rdlane(xld2, 2 * i + 1), a1);
            }
            hsp[cpol][lane] = __low2float(a0) + __high2float(a0)
                            + __low2float(a1) + __high2float(a1);
        }
        {            // E-matvec quarter-slice
            uint32 xld = spk[qt * 32 + (lane & 31)];
            __half2 m0 = hzero, m1 = hzero, m2 = hzero, m3 = hzero;
            #pragma unroll
            for (int i = 0; i < 8; ++i) {
                m0 = pkfma(Ereg[4 * i + 0], rdlane(xld, 4 * i + 0), m0);
                m1 = pkfma(Ereg[4 * i + 1], rdlane(xld, 4 * i + 1), m1);
                m2 = pkfma(Ereg[4 * i + 2], rdlane(xld, 4 * i + 2), m2);
                m3 = pkfma(Ereg[4 * i + 3], rdlane(xld, 4 * i + 3), m3);
            }
            float y = (__low2float(m0) + __high2float(m0))
                    + (__low2float(m1) + __high2float(m1))
                    + (__low2float(m2) + __high2float(m2))
                    + (__low2float(m3) + __high2float(m3));
            part[qt][r] = y;
        }
        if (t < NN) out[(size_t)k * NN + t] = xr;
        if (t >= 1016) td[nxt][t - 1016] = tdp;
        asm volatile("s_waitcnt lgkmcnt(0)\ns_barrier" ::: "memory");

        // ---- Phase B ----
        if (t < NN) {            // x-update with a_k (ready since step k-1)
            float a = aS[cur];
            float S0 = td[cur][0], S1 = td[cur][1], S2 = td[cur][2], S3 = td[cur][3];
            float y = ((part[0][t] + part[1][t]) + (part[2][t] + part[3][t])) * 0.015625f;
            float xn = xr + y + cer
                     + S0 * g0r + S1 * g1r + S2 * g2r + S3 * g3r - a * qr;
            xr = xn;
            sph[t] = __float2half_rn(xn - 23.359f);
        } else if (w == 4) {     // a_{k+1} = policy(x_k, t_{k+1}) — latency hidden
            float s = 0.0f;
            #pragma unroll
            for (int i = 0; i < 8; ++i) s += hsp[i][lane];
            float h = tanhf(s + b1r + w1f0 * td[nxt][4] + w1f1 * td[nxt][5]
                                  + w1f2 * td[nxt][6] + w1f3 * td[nxt][7]);
            float v = w2r * h;
            v += __shfl_xor(v, 1);  v += __shfl_xor(v, 2);  v += __shfl_xor(v, 4);
            v += __shfl_xor(v, 8);  v += __shfl_xor(v, 16); v += __shfl_xor(v, 32);
            if (lane == 0) aS[nxt] = sigm(v);
        }
        asm volatile("s_waitcnt lgkmcnt(0)\ns_barrier" ::: "memory");
    }
}

extern "C" void kernel_launch(void* const* d_in, const int* in_sizes, int n_in,
                              void* d_out, int out_size, void* d_ws, size_t ws_size,
                              hipStream_t stream)
{
    (void)n_in; (void)out_size; (void)ws_size;
    const float* tev     = (const float*)d_in[0];
    const float* A       = (const float*)d_in[1];
    const float* B       = (const float*)d_in[2];
    const float* cooling = (const float*)d_in[3];
    const float* w1      = (const float*)d_in[4];
    const float* b1      = (const float*)d_in[5];
    const float* w2      = (const float*)d_in[6];
    const float* tts     = (const float*)d_in[7];
    const float* tvals   = (const float*)d_in[8];
    const int T     = in_sizes[0];
    const int ntout = in_sizes[7];

    float* out = (float*)d_out;
    float* ws  = (float*)d_ws;
    float*  R    = ws;                          // 65536 floats
    float*  gq   = ws + 65536;                  // 1536 floats
    uint32* w1pk = (uint32*)(ws + 67072);       // 8192 dwords
    float*  td   = ws + 75264;                  // T*8 floats
    float* P1 = out;                            // GEMM ping-pong (rewritten by k_main)
    float* P2 = out + 65536;
    size_t outN = (size_t)T * NN;
    uint32* Epk = (uint32*)(out + outN - 32768);  // 128 KB tail, read before overwritten

    hipLaunchKernelGGL(k_affine, dim3(256), dim3(256), 0, stream, A, P1, tev, 4);
    hipLaunchKernelGGL(k_gemm,   dim3(256), dim3(256), 0, stream, A, P1, P2, tev, 3);
    hipLaunchKernelGGL(k_gemm,   dim3(256), dim3(256), 0, stream, A, P2, P1, tev, 2);
    hipLaunchKernelGGL(k_gemm,   dim3(256), dim3(256), 0, stream, A, P1, R,  tev, 1);
    hipLaunchKernelGGL(k_packE,  dim3(128), dim3(256), 0, stream, R, Epk);
    hipLaunchKernelGGL(k_packW,  dim3(32),  dim3(256), 0, stream, w1, w1pk);
    hipLaunchKernelGGL(k_prep_vec, dim3(1), dim3(256), 0, stream, A, B, cooling, tev, R, gq);
    hipLaunchKernelGGL(k_time, dim3((T + 255) / 256), dim3(256), 0, stream,
                       tev, tts, tvals, td, T, ntout);
    hipLaunchKernelGGL(k_main, dim3(1), dim3(1024), 0, stream,
                       td, Epk, w1pk, gq, b1, w2, w1, out, T);
}